// Round 3
// baseline (741.603 us; speedup 1.0000x reference)
//
#include <hip/hip_runtime.h>
#include <hip/hip_bf16.h>

#define B_   2
#define S_   2048
#define H_   2048
#define D_   256
#define NH_  8

typedef unsigned short u16;
typedef __bf16 bf16x8 __attribute__((ext_vector_type(8)));
typedef float f32x4 __attribute__((ext_vector_type(4)));
typedef unsigned int uint4v __attribute__((ext_vector_type(4)));
typedef unsigned int uint2v __attribute__((ext_vector_type(2)));

#define AS1 __attribute__((address_space(1)))
#define AS3 __attribute__((address_space(3)))

__device__ __forceinline__ u16 f2bf(float x) {
  union { float f; unsigned u; } v; v.f = x;
  unsigned u = v.u;
  u += 0x7FFFu + ((u >> 16) & 1u);   // round-to-nearest-even
  return (u16)(u >> 16);
}
__device__ __forceinline__ float bf2f(u16 x) {
  union { unsigned u; float f; } v; v.u = ((unsigned)x) << 16;
  return v.f;
}

// async 16B global -> LDS (m97; LDS dest = wave-uniform base + lane*16)
__device__ __forceinline__ void gld_lds16(const u16* g, u16* l) {
  __builtin_amdgcn_global_load_lds((const AS1 unsigned int*)g,
                                   (AS3 unsigned int*)l, 16, 0, 0);
}

// ---------------------------------------------------------------------------
// Tiled NT GEMM: C[M,N] = A[M,K]*B[N,K]^T, bf16 MFMA 16x16x32, fp32 acc.
// BM=BN=128, BK=64 (m97 recipe: 32KB staging LDS, 32 MFMA per barrier pair).
// 256 thr = 4 waves 2x2; wave computes 64x64 via 4x4 MFMA.
// Layouts (m89/m91): A[m=lane&15][k=quad*8+j], B[k=quad*8+j][n=lane&15],
// C/D col=lane&15 row=quad*4+reg.
// bf16-output modes stage C through LDS for 16B-coalesced stores.
// ---------------------------------------------------------------------------
#define BM 128
#define BN 128
#define BK 64
#define CPAD 132   // C-tile LDS row stride (u16): 2-way max on readback

enum GemmMode { MODE_PROJ = 0, MODE_QK = 1, MODE_PV = 2, MODE_WO = 3 };

template <int MODE>
__global__ __launch_bounds__(256)
void gemm_nt(const u16* __restrict__ A, const u16* __restrict__ Bb,
             void* __restrict__ Cp, float* __restrict__ rows,
             int K, int lda, int ldb, int ldc)
{
  const int bn = blockIdx.x, bm = blockIdx.y, bz = blockIdx.z;
  if (MODE == MODE_QK && bn > bm) return;   // fully-masked causal tile
  const int m0 = bm * BM, n0 = bn * BN;

  const u16* Ap = A;
  const u16* Bp = Bb;
  float* Cf = (float*)Cp;
  u16*   Cu = (u16*)Cp;

  if constexpr (MODE == MODE_QK) {
    Ap   += (size_t)bz * S_ * D_;           // Q slab (b,h)
    Bp   += (size_t)(bz >> 3) * S_ * D_;    // K slab (b)
    Cu   += (size_t)bz * S_ * S_;           // E slab (bf16, unnormalized exp)
    rows += (size_t)bz * S_;
  } else if constexpr (MODE == MODE_PV) {
    Ap   += (size_t)bz * S_ * S_;           // E slab (bf16)
    Bp   += (size_t)(bz >> 3) * D_ * S_;    // V^T slab (b)
    Cu   += (size_t)(bz >> 3) * S_ * (NH_ * D_) + (size_t)(bz & 7) * D_;
    rows += (size_t)bz * S_;
  }

  int Keff = K;
  if constexpr (MODE == MODE_PV) {          // E[m][k]==0 for k>m
    int lim = (bm + 1) * BM;
    Keff = lim < K ? lim : K;
  }

  // staging LDS (32 KB) aliased with C writeback tile (33 KB)
  __shared__ __align__(16) char smem[CPAD * BM * 2];
  u16* sA = (u16*)smem;                     // [BM][BK]
  u16* sB = sA + BM * BK;                   // [BN][BK]
  u16* sC = (u16*)smem;                     // [BM][CPAD]

  const int tid  = threadIdx.x;
  const int lane = tid & 63;
  const int quad = lane >> 4;
  const int l16  = lane & 15;
  const int wave = tid >> 6;
  const int wm   = (wave >> 1) << 6;
  const int wn   = (wave & 1) << 6;

  f32x4 acc[4][4] = {};

  for (int kt = 0; kt < Keff; kt += BK) {
    #pragma unroll
    for (int i = 0; i < 4; i++) {           // A tile 128x64: 1024 16B chunks
      int c = tid + i * 256;
      gld_lds16(Ap + (size_t)(m0 + (c >> 3)) * lda + kt + (c & 7) * 8, &sA[c * 8]);
    }
    #pragma unroll
    for (int i = 0; i < 4; i++) {           // B tile 128x64
      int c = tid + i * 256;
      gld_lds16(Bp + (size_t)(n0 + (c >> 3)) * ldb + kt + (c & 7) * 8, &sB[c * 8]);
    }
    __syncthreads();                        // drains vmcnt (compiler-inserted)

    #pragma unroll
    for (int ks = 0; ks < BK; ks += 32) {
      bf16x8 af[4], bfr[4];
      #pragma unroll
      for (int i = 0; i < 4; i++)
        af[i] = *(const bf16x8*)(&sA[(wm + i * 16 + l16) * BK + ks + quad * 8]);
      #pragma unroll
      for (int j = 0; j < 4; j++)
        bfr[j] = *(const bf16x8*)(&sB[(wn + j * 16 + l16) * BK + ks + quad * 8]);
      #pragma unroll
      for (int i = 0; i < 4; i++)
        #pragma unroll
        for (int j = 0; j < 4; j++)
          acc[i][j] = __builtin_amdgcn_mfma_f32_16x16x32_bf16(af[i], bfr[j], acc[i][j], 0, 0, 0);
    }
    __syncthreads();
  }

  // ---- epilogue ----
  const float SCL2 = 0.0625f * 1.44269504088896340736f;  // D^-0.5 * log2(e)

  if constexpr (MODE == MODE_WO) {          // fp32 direct stores
    #pragma unroll
    for (int i = 0; i < 4; i++)
      #pragma unroll
      for (int r = 0; r < 4; r++) {
        int m = m0 + wm + i * 16 + quad * 4 + r;
        #pragma unroll
        for (int j = 0; j < 4; j++)
          Cf[(size_t)m * ldc + n0 + wn + j * 16 + l16] = acc[i][j][r];
      }
    return;
  }

  // bf16 modes: acc -> sC (padded) -> coalesced 16B stores
  #pragma unroll
  for (int i = 0; i < 4; i++) {
    #pragma unroll
    for (int r = 0; r < 4; r++) {
      const int mr = wm + i * 16 + quad * 4 + r;      // row within tile
      const int m  = m0 + mr;
      if constexpr (MODE == MODE_QK) {
        float rs = 0.f;
        #pragma unroll
        for (int j = 0; j < 4; j++) {
          int n = n0 + wn + j * 16 + l16;
          float e = (n <= m) ? exp2f(acc[i][j][r] * SCL2) : 0.f;
          rs += e;
          sC[mr * CPAD + wn + j * 16 + l16] = f2bf(e);
        }
        #pragma unroll
        for (int o = 1; o < 16; o <<= 1) rs += __shfl_xor(rs, o, 64);
        if (l16 == 0) atomicAdd(&rows[m], rs);
      } else if constexpr (MODE == MODE_PV) {
        float inv = 1.0f / rows[m];
        #pragma unroll
        for (int j = 0; j < 4; j++)
          sC[mr * CPAD + wn + j * 16 + l16] = f2bf(acc[i][j][r] * inv);
      } else {
        #pragma unroll
        for (int j = 0; j < 4; j++)
          sC[mr * CPAD + wn + j * 16 + l16] = f2bf(acc[i][j][r]);
      }
    }
  }
  __syncthreads();
  #pragma unroll
  for (int p = 0; p < 8; p++) {             // 16 rows per pass, 256B/row
    int row = p * 16 + (tid >> 4);
    int col = (tid & 15) * 8;
    uint4v x = *(const uint4v*)(&sC[row * CPAD + col]);
    *(uint4v*)(Cu + (size_t)(m0 + row) * ldc + n0 + col) = x;
  }
}

// ---------------------------------------------------------------------------
// prep: X fp32->bf16  +  4 weight transpose-converts, one launch.
// blocks [0,8192) convert; [8192,12288) Wq; [12288,12800) Wk;
// [12800,13312) Wv; [13312,17408) Wo.
// ---------------------------------------------------------------------------
__device__ __forceinline__ void tconv_tile(const float* __restrict__ src,
                                           u16* __restrict__ dst,
                                           int K, int N, int bx, int by)
{
  __shared__ float t[32][33];
  int n0 = bx * 32, k0 = by * 32;
  int c = threadIdx.x & 31, r = threadIdx.x >> 5;
  #pragma unroll
  for (int rr = 0; rr < 32; rr += 8)
    t[r + rr][c] = src[(size_t)(k0 + r + rr) * N + n0 + c];
  __syncthreads();
  #pragma unroll
  for (int rr = 0; rr < 32; rr += 8)
    dst[(size_t)(n0 + r + rr) * K + k0 + c] = f2bf(t[c][r + rr]);
}

__global__ __launch_bounds__(256)
void prep_kernel(const float* __restrict__ X,
                 const float* __restrict__ Wq, const float* __restrict__ Wk,
                 const float* __restrict__ Wv, const float* __restrict__ Wo,
                 u16* __restrict__ Xbf, u16* __restrict__ WT, u16* __restrict__ WoT)
{
  int b = blockIdx.x;
  if (b < 8192) {
    int i = b * 256 + threadIdx.x;          // 2,097,152 float4 groups exactly
    float4 f = ((const float4*)X)[i];
    uint2v p;
    p.x = (unsigned)f2bf(f.x) | ((unsigned)f2bf(f.y) << 16);
    p.y = (unsigned)f2bf(f.z) | ((unsigned)f2bf(f.w) << 16);
    ((uint2v*)Xbf)[i] = p;
  } else if (b < 12288) {
    int t = b - 8192;  tconv_tile(Wq, WT, 2048, 2048, t & 63, t >> 6);
  } else if (b < 12800) {
    int t = b - 12288; tconv_tile(Wk, WT + 2048 * 2048, 2048, 256, t & 7, t >> 3);
  } else if (b < 13312) {
    int t = b - 12800; tconv_tile(Wv, WT + 2304 * 2048, 2048, 256, t & 7, t >> 3);
  } else {
    int t = b - 13312; tconv_tile(Wo, WoT, 2048, 2048, t & 63, t >> 6);
  }
}

// ---------------------------------------------------------------------------
// stage2: RoPE(Q), RoPE(K), V-transpose, Rows zeroing — one launch.
// blocks [0,32768) ropeQ; [32768,36864) ropeK; [36864,37888) transV;
// [37888,37920) zero Rows.
// ---------------------------------------------------------------------------
__global__ __launch_bounds__(256)
void stage2_kernel(const u16* __restrict__ qkv, const float* __restrict__ cosb,
                   const float* __restrict__ sinb, u16* __restrict__ qout,
                   u16* __restrict__ kout, u16* __restrict__ vt,
                   float* __restrict__ rows)
{
  int blk = blockIdx.x;
  if (blk < 32768) {                        // RoPE Q
    int h = blk & 7, bs = blk >> 3;
    int b = bs >> 11, s = bs & (S_ - 1);
    int d = threadIdx.x;
    size_t base = (size_t)bs * 2560 + (size_t)h * D_;
    float qv = bf2f(qkv[base + d]);
    float qp = bf2f(qkv[base + (d ^ 128)]);
    float c  = cosb[(size_t)bs * D_ + d];
    float sn = sinb[(size_t)bs * D_ + d];
    float rot = (d < 128) ? -qp : qp;
    qout[(((size_t)b * NH_ + h) * S_ + s) * D_ + d] = f2bf(qv * c + rot * sn);
  } else if (blk < 36864) {                 // RoPE K
    int bs = blk - 32768;
    int d = threadIdx.x;
    size_t base = (size_t)bs * 2560 + 2048;
    float kv = bf2f(qkv[base + d]);
    float kp = bf2f(qkv[base + (d ^ 128)]);
    float c  = cosb[(size_t)bs * D_ + d];
    float sn = sinb[(size_t)bs * D_ + d];
    float rot = (d < 128) ? -kp : kp;
    kout[(size_t)bs * D_ + d] = f2bf(kv * c + rot * sn);
  } else if (blk < 37888) {                 // V transpose -> (B,D,S)
    __shared__ u16 t[32][34];
    int g = blk - 36864;                    // 8 x 64 x 2
    int b = g >> 9, rem = g & 511;
    int d0 = (rem & 7) * 32, s0 = (rem >> 3) * 32;
    int c = threadIdx.x & 31, r = threadIdx.x >> 5;
    #pragma unroll
    for (int rr = 0; rr < 32; rr += 8)
      t[r + rr][c] = qkv[(size_t)(b * S_ + s0 + r + rr) * 2560 + 2304 + d0 + c];
    __syncthreads();
    #pragma unroll
    for (int rr = 0; rr < 32; rr += 8)
      vt[(size_t)b * D_ * S_ + (size_t)(d0 + r + rr) * S_ + s0 + c] = t[c][r + rr];
  } else {                                  // zero Rows (32768 floats)
    int g = blk - 37888;
    float4 z = {0.f, 0.f, 0.f, 0.f};
    ((float4*)rows)[g * 256 + threadIdx.x] = z;
  }
}

// ---------------------------------------------------------------------------
// P[r][k] = E[r][k] * inv(rowsum[r]) fp32 (zeros above diagonal).
// ---------------------------------------------------------------------------
__global__ __launch_bounds__(256)
void normalize_p(const u16* __restrict__ E, const float* __restrict__ rows,
                 float* __restrict__ P)
{
  const int r = blockIdx.x;
  const int q = r & (S_ - 1);
  const u16* e = E + (size_t)r * S_;
  float* p = P + (size_t)r * S_;
  const float inv = 1.0f / rows[r];
  const int k0 = threadIdx.x * 8;

  float4 lo = {0.f, 0.f, 0.f, 0.f}, hi = {0.f, 0.f, 0.f, 0.f};
  if (k0 <= q) {
    uint4v u = *(const uint4v*)(e + k0);
    float v[8];
    v[0] = bf2f(u.x & 0xffff); v[1] = bf2f(u.x >> 16);
    v[2] = bf2f(u.y & 0xffff); v[3] = bf2f(u.y >> 16);
    v[4] = bf2f(u.z & 0xffff); v[5] = bf2f(u.z >> 16);
    v[6] = bf2f(u.w & 0xffff); v[7] = bf2f(u.w >> 16);
    lo.x = (k0 + 0 <= q) ? v[0] * inv : 0.f;
    lo.y = (k0 + 1 <= q) ? v[1] * inv : 0.f;
    lo.z = (k0 + 2 <= q) ? v[2] * inv : 0.f;
    lo.w = (k0 + 3 <= q) ? v[3] * inv : 0.f;
    hi.x = (k0 + 4 <= q) ? v[4] * inv : 0.f;
    hi.y = (k0 + 5 <= q) ? v[5] * inv : 0.f;
    hi.z = (k0 + 6 <= q) ? v[6] * inv : 0.f;
    hi.w = (k0 + 7 <= q) ? v[7] * inv : 0.f;
  }
  *(float4*)(p + k0)     = lo;
  *(float4*)(p + k0 + 4) = hi;
}

// ---------------------------------------------------------------------------
extern "C" void kernel_launch(void* const* d_in, const int* in_sizes, int n_in,
                              void* d_out, int out_size, void* d_ws, size_t ws_size,
                              hipStream_t stream)
{
  const float* X    = (const float*)d_in[0];
  const float* cosb = (const float*)d_in[1];
  const float* sinb = (const float*)d_in[2];
  // d_in[3] = attention_mask (pure causal; synthesized in-kernel)
  const float* Wq   = (const float*)d_in[4];
  const float* Wk   = (const float*)d_in[5];
  const float* Wv   = (const float*)d_in[6];
  const float* Wo   = (const float*)d_in[7];

  float* outO = (float*)d_out;                               // (B,S,H) fp32
  float* outP = outO + (size_t)B_ * S_ * H_;                 // (B,NH,S,S) fp32

  // workspace layout (u16 elems)
  u16* ws     = (u16*)d_ws;
  u16* Xbf    = ws;                          //  8,388,608  X bf16 (B*S, H)
  u16* WT     = Xbf    + 8388608;            //  5,242,880  [Wq|Wk|Wv]^T (2560,2048)
  u16* WoT    = WT     + 5242880;            //  4,194,304  Wo^T (2048,2048)
  u16* QKVraw = WoT    + 4194304;            // 10,485,760  X@W (B*S, 2560)
  u16* Qbf    = QKVraw + 10485760;           //  8,388,608  (B,NH,S,D) post-RoPE
  u16* Kbf    = Qbf    + 8388608;            //  1,048,576  (B,S,D)   post-RoPE
  u16* VT     = Kbf    + 1048576;            //  1,048,576  (B,D,S)
  u16* AObf   = VT     + 1048576;            //  8,388,608  (B,S,NH*D)
  u16* Ebf    = AObf   + 8388608;            // 67,108,864  unnormalized exp (B,NH,S,S)
  float* Rows = (float*)(Ebf + 67108864);    //     32,768  fp32 row sums

  // 1. preprocessing: X->bf16 + weight transposes (one launch)
  prep_kernel<<<17408, 256, 0, stream>>>(X, Wq, Wk, Wv, Wo, Xbf, WT, WoT);
  // 2. fused QKV projection (one GEMM, N=2560)
  gemm_nt<MODE_PROJ><<<dim3(20, 32, 1), 256, 0, stream>>>(
      Xbf, WT, QKVraw, nullptr, 2048, 2048, 2048, 2560);
  // 3. RoPE + V transpose + Rows zeroing (one launch)
  stage2_kernel<<<37920, 256, 0, stream>>>(QKVraw, cosb, sinb, Qbf, Kbf, VT, Rows);
  // 4. E = exp(QK^T*scale) bf16 lower-tri, rowsums via atomics
  gemm_nt<MODE_QK><<<dim3(16, 16, 16), 256, 0, stream>>>(
      Qbf, Kbf, Ebf, Rows, 256, 256, 256, 2048);
  // 5. P (fp32, d_out) = E * inv(rowsum)
  normalize_p<<<32768, 256, 0, stream>>>(Ebf, Rows, outP);
  // 6. attn_out = (E @ V) * inv(rowsum), K truncated at diagonal
  gemm_nt<MODE_PV><<<dim3(2, 16, 16), 256, 0, stream>>>(
      Ebf, VT, AObf, Rows, 2048, 2048, 2048, 2048);
  // 7. @ Wo -> fp32 attn_output
  gemm_nt<MODE_WO><<<dim3(16, 32, 1), 256, 0, stream>>>(
      AObf, WoT, outO, nullptr, 2048, 2048, 2048, 2048);
}